// Round 1
// 413.776 us; speedup vs baseline: 1.1911x; 1.1911x over previous
//
#include <hip/hip_runtime.h>
#include <math.h>

// Problem constants (GPT2 decode attention, fp32)
#define BATCH   32
#define NH      16
#define HD      64      // head dim
#define T_ALL   2048    // cached 2047 + 1 new
#define T_CACHE 2047
#define HID     1024
#define H3      3072
#define QK_SCALE 0.125f // 64^-0.5
#define NCHUNK  8       // token chunks per (b,h) for flash-decoding split
#define CHTOK   256     // tokens per chunk
#define KSPLIT  8       // k-split for the GEMV kernels

// native 16B vector for nontemporal builtins
typedef float f4 __attribute__((ext_vector_type(4)));

// ---------------------------------------------------------------------------
// GEMV: out_part[ks][b][c] = sum_{k in split ks} X[b][k] * W[k][c]
// One thread owns column c for ALL 32 batches -> W is read once from HBM.
// (unchanged from baseline: accumulation order preserved bit-exactly)
// ---------------------------------------------------------------------------
__global__ __launch_bounds__(256) void gemv_part_kernel(
    const float* __restrict__ X, const float* __restrict__ W,
    float* __restrict__ part, int N, int Kdim)
{
    const int c  = blockIdx.x * 256 + threadIdx.x;
    const int ks = blockIdx.y;
    const int kchunk = Kdim / KSPLIT;
    float acc[BATCH];
#pragma unroll
    for (int b = 0; b < BATCH; ++b) acc[b] = 0.f;
    const int k0 = ks * kchunk;
    for (int k = k0; k < k0 + kchunk; ++k) {
        const float w = W[(size_t)k * N + c];
#pragma unroll
        for (int b = 0; b < BATCH; ++b)
            acc[b] = fmaf(X[b * Kdim + k], w, acc[b]);
    }
#pragma unroll
    for (int b = 0; b < BATCH; ++b)
        part[((size_t)ks * BATCH + b) * N + c] = acc[b];
}

__global__ __launch_bounds__(256) void gemv_reduce_kernel(
    const float* __restrict__ part, const float* __restrict__ bias,
    float* __restrict__ out, int N)
{
    const int c = blockIdx.x * 256 + threadIdx.x;
    const int b = blockIdx.y;
    float acc = bias[c];
#pragma unroll
    for (int ks = 0; ks < KSPLIT; ++ks)
        acc += part[((size_t)ks * BATCH + b) * N + c];
    out[(size_t)b * N + c] = acc;
}

// ---------------------------------------------------------------------------
// Fused cache-copy + flash-decoding attention chunk, v2.
// grid = (NCHUNK, NH, BATCH), block = 256 (4 waves).
// Wave layout: lane = tgrp*16 + dgrp. Each iteration a wave handles 4
// consecutive tokens (tgrp) x 16 float4 dim-groups (dgrp) = 1 KiB coalesced.
//
// v2 changes vs baseline (all numerics-identical):
//  - per-wave loop split: softmax update only for the `nat` windows that can
//    contain a valid token (tb < slen); the rest is a branch-free pure copy.
//    (skipped windows were exact no-ops before: alpha=1, p=0)
//  - GUARD specialization: only the single tail wave (t0==1984) carries the
//    t < T_CACHE predication; all other waves get straight-line load/store.
//  - nontemporal loads/stores on the 1 GB one-touch K/V stream (no L2 reuse).
// ---------------------------------------------------------------------------
template<bool GUARD>
__device__ __forceinline__ void copy_step(
    int t, int dgrp,
    const f4* __restrict__ kc4, const f4* __restrict__ vc4,
    f4* __restrict__ Ko4, f4* __restrict__ Vo4,
    f4& kv, f4& vv)
{
    kv = (f4){0.f, 0.f, 0.f, 0.f};
    vv = (f4){0.f, 0.f, 0.f, 0.f};
    if (!GUARD || (t < T_CACHE)) {
        kv = __builtin_nontemporal_load(kc4 + t * 16 + dgrp);
        vv = __builtin_nontemporal_load(vc4 + t * 16 + dgrp);
        __builtin_nontemporal_store(kv, Ko4 + t * 16 + dgrp);
        __builtin_nontemporal_store(vv, Vo4 + t * 16 + dgrp);
    }
}

template<bool GUARD>
__device__ __forceinline__ void attn_step(
    int t, int slen, const f4 q4, const f4 kv, const f4 vv,
    float& m, float& l, f4& o)
{
    // NB: token T_ALL-1 (t==2047, not in cache) must be invalid even when
    // slen==2048 — it is handled with the fresh k/v by the combine kernel.
    bool valid = (t < slen);
    if (GUARD) valid = valid && (t < T_CACHE);
    // dot(q, K[t]) across the 16-lane dim group
    float s = kv.x * q4.x + kv.y * q4.y + kv.z * q4.z + kv.w * q4.w;
    s += __shfl_xor(s, 1);
    s += __shfl_xor(s, 2);
    s += __shfl_xor(s, 4);
    s += __shfl_xor(s, 8);
    s = valid ? s * QK_SCALE : -1e30f;
    // wave-wide max over the 4 tokens
    float mx = s;
    mx = fmaxf(mx, __shfl_xor(mx, 16));
    mx = fmaxf(mx, __shfl_xor(mx, 32));
    const float mn    = fmaxf(m, mx);
    const float alpha = __expf(m - mn);          // ==1 when both -1e30
    const float p     = valid ? __expf(s - mn) : 0.f;
    float ps = p;
    ps += __shfl_xor(ps, 16);
    ps += __shfl_xor(ps, 32);
    l = l * alpha + ps;
    m = mn;
    o.x = o.x * alpha + p * vv.x;
    o.y = o.y * alpha + p * vv.y;
    o.z = o.z * alpha + p * vv.z;
    o.w = o.w * alpha + p * vv.w;
}

__global__ __launch_bounds__(256) void fused_copy_attn_kernel(
    const float* __restrict__ kc, const float* __restrict__ vc,
    const float* __restrict__ qkv, const int* __restrict__ seq_lens,
    float* __restrict__ Kout, float* __restrict__ Vout,
    float* __restrict__ Pm, float* __restrict__ Pl, float* __restrict__ Po)
{
    const int chunk = blockIdx.x;
    const int h     = blockIdx.y;
    const int b     = blockIdx.z;
    const int tid   = threadIdx.x;
    const int wave  = tid >> 6;
    const int lane  = tid & 63;
    const int dgrp  = lane & 15;   // which float4 of the 64-dim row
    const int tgrp  = lane >> 4;   // which of 4 tokens in this iteration

    const int bh   = b * NH + h;
    const int slen = seq_lens[b];

    const f4 q4 = ((const f4*)(qkv + (size_t)b * H3 + h * HD))[dgrp];

    const f4* kc4 = (const f4*)(kc + (size_t)bh * T_CACHE * HD);
    const f4* vc4 = (const f4*)(vc + (size_t)bh * T_CACHE * HD);
    f4* Ko4 = (f4*)(Kout + (size_t)bh * T_ALL * HD);
    f4* Vo4 = (f4*)(Vout + (size_t)bh * T_ALL * HD);

    float m = -1e30f, l = 0.f;
    f4 o = {0.f, 0.f, 0.f, 0.f};

    const int t0 = chunk * CHTOK + wave * 64;
    // number of 4-token windows with any potentially-valid token
    const int nat = min(16, max(0, (slen - t0 + 3) >> 2));

    if (t0 + 63 < T_CACHE) {            // all waves except the single tail wave
        int i = 0;
#pragma unroll 4
        for (; i < nat; ++i) {
            const int t = t0 + i * 4 + tgrp;
            f4 kv, vv;
            copy_step<false>(t, dgrp, kc4, vc4, Ko4, Vo4, kv, vv);
            attn_step<false>(t, slen, q4, kv, vv, m, l, o);
        }
#pragma unroll 4
        for (; i < 16; ++i) {           // pure streaming copy, branch-free
            const int t = t0 + i * 4 + tgrp;
            f4 kv, vv;
            copy_step<false>(t, dgrp, kc4, vc4, Ko4, Vo4, kv, vv);
        }
    } else {                            // tail wave: t0 == 1984, contains t == 2047
        int i = 0;
#pragma unroll 4
        for (; i < nat; ++i) {
            const int t = t0 + i * 4 + tgrp;
            f4 kv, vv;
            copy_step<true>(t, dgrp, kc4, vc4, Ko4, Vo4, kv, vv);
            attn_step<true>(t, slen, q4, kv, vv, m, l, o);
        }
#pragma unroll 4
        for (; i < 16; ++i) {
            const int t = t0 + i * 4 + tgrp;
            f4 kv, vv;
            copy_step<true>(t, dgrp, kc4, vc4, Ko4, Vo4, kv, vv);
        }
    }

    // reduce o over the 4 token groups (all lanes end with their dgrp's total)
    o.x += __shfl_xor(o.x, 16); o.x += __shfl_xor(o.x, 32);
    o.y += __shfl_xor(o.y, 16); o.y += __shfl_xor(o.y, 32);
    o.z += __shfl_xor(o.z, 16); o.z += __shfl_xor(o.z, 32);
    o.w += __shfl_xor(o.w, 16); o.w += __shfl_xor(o.w, 32);

    __shared__ float sm[4], sl[4];
    __shared__ f4 so4[4][16];
    if (lane == 0) { sm[wave] = m; sl[wave] = l; }
    if (lane < 16) so4[wave][dgrp] = o;
    __syncthreads();

    if (tid < HD) {
        const int d = tid;
        const float m0 = sm[0], m1 = sm[1], m2 = sm[2], m3 = sm[3];
        const float mc = fmaxf(fmaxf(m0, m1), fmaxf(m2, m3));
        const float e0 = __expf(m0 - mc), e1 = __expf(m1 - mc);
        const float e2 = __expf(m2 - mc), e3 = __expf(m3 - mc);
        const float lc = sl[0]*e0 + sl[1]*e1 + sl[2]*e2 + sl[3]*e3;
        const float* so = (const float*)so4;   // [4][64]
        const float oc = so[0*HD + d]*e0 + so[1*HD + d]*e1
                       + so[2*HD + d]*e2 + so[3*HD + d]*e3;
        const int pb = bh * NCHUNK + chunk;
        Po[(size_t)pb * HD + d] = oc;
        if (d == 0) { Pm[pb] = mc; Pl[pb] = lc; }
    }
}

// ---------------------------------------------------------------------------
// Combine chunk partials + the always-visible new token; also append the new
// k/v row to the output caches. grid = 512 (b*NH+h), block = 64 (one wave).
// ---------------------------------------------------------------------------
__global__ __launch_bounds__(64) void combine_kernel(
    const float* __restrict__ qkv,
    const float* __restrict__ Pm, const float* __restrict__ Pl,
    const float* __restrict__ Po,
    float* __restrict__ attn, float* __restrict__ Kout, float* __restrict__ Vout)
{
    const int bh = blockIdx.x;
    const int b = bh >> 4, h = bh & 15;
    const int d = threadIdx.x;     // 0..63

    const float* qb = qkv + (size_t)b * H3;
    const float qd = qb[h * HD + d];
    const float kn = qb[HID  + h * HD + d];
    const float vn = qb[2*HID + h * HD + d];

    // append new token row (position T_ALL-1)
    Kout[((size_t)bh * T_ALL + (T_ALL - 1)) * HD + d] = kn;
    Vout[((size_t)bh * T_ALL + (T_ALL - 1)) * HD + d] = vn;

    // new-token score (always valid)
    float s = qd * kn;
    s += __shfl_xor(s, 1);
    s += __shfl_xor(s, 2);
    s += __shfl_xor(s, 4);
    s += __shfl_xor(s, 8);
    s += __shfl_xor(s, 16);
    s += __shfl_xor(s, 32);
    s *= QK_SCALE;

    float mg = s;
#pragma unroll
    for (int c = 0; c < NCHUNK; ++c)
        mg = fmaxf(mg, Pm[bh * NCHUNK + c]);

    float L   = __expf(s - mg);   // p_new
    float acc = L * vn;
#pragma unroll
    for (int c = 0; c < NCHUNK; ++c) {
        const float e = __expf(Pm[bh * NCHUNK + c] - mg);
        acc += Po[(size_t)(bh * NCHUNK + c) * HD + d] * e;
        L   += Pl[bh * NCHUNK + c] * e;
    }
    attn[(size_t)b * HID + h * HD + d] = acc / L;
}

// ---------------------------------------------------------------------------
extern "C" void kernel_launch(void* const* d_in, const int* in_sizes, int n_in,
                              void* d_out, int out_size, void* d_ws, size_t ws_size,
                              hipStream_t stream)
{
    const float* hs       = (const float*)d_in[0];   // [32,1,1024]
    const float* kc       = (const float*)d_in[1];   // [32,16,2047,64]
    const float* vc       = (const float*)d_in[2];   // [32,16,2047,64]
    // d_in[3] block_tables: unused by the reference math
    const int*   seq_lens = (const int*)d_in[4];     // [32]
    // d_in[5] max_seq_len: == 2048, hardcoded
    const float* W_attn   = (const float*)d_in[6];   // [1024,3072]
    const float* b_attn   = (const float*)d_in[7];   // [3072]
    const float* W_proj   = (const float*)d_in[8];   // [1024,1024]
    const float* b_proj   = (const float*)d_in[9];   // [1024]

    float* out_attn = (float*)d_out;                           // 32*1024
    float* Kout = out_attn + (size_t)BATCH * HID;              // 32*16*2048*64
    float* Vout = Kout + (size_t)BATCH * NH * T_ALL * HD;

    // workspace layout (floats)
    float* w = (float*)d_ws;
    float* w_qkv_part  = w;                       // 8*32*3072  = 786432
    float* w_qkv       = w_qkv_part + (size_t)KSPLIT * BATCH * H3;   // 98304
    float* w_Pm        = w_qkv + (size_t)BATCH * H3;                 // 4096
    float* w_Pl        = w_Pm + BATCH * NH * NCHUNK;                 // 4096
    float* w_Po        = w_Pl + BATCH * NH * NCHUNK;                 // 262144
    float* w_attnvec   = w_Po + (size_t)BATCH * NH * NCHUNK * HD;    // 32768
    float* w_proj_part = w_attnvec + (size_t)BATCH * HID;            // 262144

    // 1) qkv = hs @ W_attn + b_attn
    gemv_part_kernel<<<dim3(H3 / 256, KSPLIT), 256, 0, stream>>>(
        hs, W_attn, w_qkv_part, H3, HID);
    gemv_reduce_kernel<<<dim3(H3 / 256, BATCH), 256, 0, stream>>>(
        w_qkv_part, b_attn, w_qkv, H3);

    // 2) fused cache copy + flash-decoding chunks
    fused_copy_attn_kernel<<<dim3(NCHUNK, NH, BATCH), 256, 0, stream>>>(
        kc, vc, w_qkv, seq_lens, Kout, Vout, w_Pm, w_Pl, w_Po);

    // 3) combine partials + new token, append new k/v rows
    combine_kernel<<<dim3(BATCH * NH), 64, 0, stream>>>(
        w_qkv, w_Pm, w_Pl, w_Po, w_attnvec, Kout, Vout);

    // 4) out = attn @ W_proj + b_proj
    gemv_part_kernel<<<dim3(HID / 256, KSPLIT), 256, 0, stream>>>(
        w_attnvec, W_proj, w_proj_part, HID, HID);
    gemv_reduce_kernel<<<dim3(HID / 256, BATCH), 256, 0, stream>>>(
        w_proj_part, b_proj, out_attn, HID);
}

// Round 2
// 271.732 us; speedup vs baseline: 1.8137x; 1.5227x over previous
//
#include <hip/hip_runtime.h>
#include <math.h>

// Problem constants (GPT2 decode attention, fp32)
#define BATCH   32
#define NH      16
#define HD      64      // head dim
#define T_ALL   2048    // cached 2047 + 1 new
#define T_CACHE 2047
#define HID     1024
#define H3      3072
#define QK_SCALE 0.125f // 64^-0.5
#define NCHUNK  8       // token chunks per (b,h) for flash-decoding split
#define CHTOK   256     // tokens per chunk
#define KSPLIT  8       // k-split for the GEMV kernels

// native 16B vector
typedef float f4 __attribute__((ext_vector_type(4)));

// ---------------------------------------------------------------------------
// GEMV part: out_part[ks][b][c] = sum_{k in split ks} X[b][k] * W[k][c]
// v3: batch dimension split across blockIdx.z (NB batches per thread) for
// 2-4x more blocks; per-column k-iteration order UNCHANGED -> bit-exact vs
// the 1147/493-us baselines. unroll 16 keeps 16 independent W loads in
// flight (was a mostly-serial 128-deep load chain at 1 wave/SIMD).
// ---------------------------------------------------------------------------
template<int NB>
__global__ __launch_bounds__(256) void gemv_part_kernel(
    const float* __restrict__ X, const float* __restrict__ W,
    float* __restrict__ part, int N, int Kdim)
{
    const int c  = blockIdx.x * 256 + threadIdx.x;
    const int ks = blockIdx.y;
    const int b0 = blockIdx.z * NB;
    const int kchunk = Kdim / KSPLIT;
    float acc[NB];
#pragma unroll
    for (int j = 0; j < NB; ++j) acc[j] = 0.f;
    const int k0 = ks * kchunk;
#pragma unroll 16
    for (int k = k0; k < k0 + kchunk; ++k) {
        const float w = W[(size_t)k * N + c];
#pragma unroll
        for (int j = 0; j < NB; ++j)
            acc[j] = fmaf(X[(b0 + j) * Kdim + k], w, acc[j]);
    }
#pragma unroll
    for (int j = 0; j < NB; ++j)
        part[((size_t)ks * BATCH + b0 + j) * N + c] = acc[j];
}

// float4 reduce (bit-exact per element: bias first, then ks ascending)
__global__ __launch_bounds__(256) void gemv_reduce_kernel(
    const float* __restrict__ part, const float* __restrict__ bias,
    float* __restrict__ out, int N)
{
    const int c4 = blockIdx.x * 256 + threadIdx.x;
    const int b  = blockIdx.y;
    const int N4 = N >> 2;
    f4 acc = ((const f4*)bias)[c4];
#pragma unroll
    for (int ks = 0; ks < KSPLIT; ++ks) {
        const f4 p = ((const f4*)part)[((size_t)ks * BATCH + b) * N4 + c4];
        acc.x += p.x; acc.y += p.y; acc.z += p.z; acc.w += p.w;
    }
    ((f4*)out)[(size_t)b * N4 + c4] = acc;
}

// ---------------------------------------------------------------------------
// Fused cache-copy + flash-decoding attention chunk, v3: two-phase.
// grid = (NCHUNK, NH, BATCH), block = 256 (4 waves).
// Wave layout: lane = tgrp*16 + dgrp; per window a wave covers 4 tokens x
// 16 float4 dim-groups = 1 KiB coalesced.
//
// v3: each wave owns 64 tokens = 16 windows, so all 16 scores fit in regs.
//  Phase K: copy K-rows + compute s[i] (independent windows, no carried
//           chain -> loads pipeline freely).
//  Then: one exact max (2 cross-tgrp shuffles, once) + one exp per window.
//        Masked lanes have s = -1e30 -> exp underflows to exactly 0.
//  Phase V: copy V-rows + o += p*v.
// This deletes all per-window online rescaling (2 exps + 4 shuffles + the
// serial m/l/o dependency chain per window) and de-interleaves the K and V
// HBM streams. Numerically closer to reference (true-max softmax).
// ---------------------------------------------------------------------------
__global__ __launch_bounds__(256) void fused_copy_attn_kernel(
    const float* __restrict__ kc, const float* __restrict__ vc,
    const float* __restrict__ qkv, const int* __restrict__ seq_lens,
    float* __restrict__ Kout, float* __restrict__ Vout,
    float* __restrict__ Pm, float* __restrict__ Pl, float* __restrict__ Po)
{
    const int chunk = blockIdx.x;
    const int h     = blockIdx.y;
    const int b     = blockIdx.z;
    const int tid   = threadIdx.x;
    const int wave  = tid >> 6;
    const int lane  = tid & 63;
    const int dgrp  = lane & 15;   // which float4 of the 64-dim row
    const int tgrp  = lane >> 4;   // which of 4 tokens per window

    const int bh   = b * NH + h;
    const int slen = seq_lens[b];

    const f4 q4 = ((const f4*)(qkv + (size_t)b * H3 + h * HD))[dgrp];

    const int t0 = chunk * CHTOK + wave * 64;
    const int tl = t0 + tgrp;                       // this lane's first token
    // windows that can contain a valid token
    const int nat  = min(16, max(0, (slen - t0 + 3) >> 2));
    const bool tail = (t0 + 63 >= T_CACHE);         // single tail wave

    const f4* kbase = (const f4*)(kc + (size_t)bh * T_CACHE * HD) + (size_t)tl * 16 + dgrp;
    const f4* vbase = (const f4*)(vc + (size_t)bh * T_CACHE * HD) + (size_t)tl * 16 + dgrp;
    f4* Kb = (f4*)(Kout + (size_t)bh * T_ALL * HD) + (size_t)tl * 16 + dgrp;
    f4* Vb = (f4*)(Vout + (size_t)bh * T_ALL * HD) + (size_t)tl * 16 + dgrp;

    float s[16];

    // ---- Phase K: copy + scores -----------------------------------------
    if (!tail) {
#pragma unroll
        for (int i = 0; i < 16; ++i) {
            const f4 kv = __builtin_nontemporal_load(kbase + i * 64);
            __builtin_nontemporal_store(kv, Kb + i * 64);
            if (i < nat) {
                float ss = kv.x * q4.x + kv.y * q4.y + kv.z * q4.z + kv.w * q4.w;
                ss += __shfl_xor(ss, 1);
                ss += __shfl_xor(ss, 2);
                ss += __shfl_xor(ss, 4);
                ss += __shfl_xor(ss, 8);
                s[i] = (tl + i * 4 < slen) ? ss * QK_SCALE : -1e30f;
            }
        }
    } else {
#pragma unroll
        for (int i = 0; i < 16; ++i) {
            const int t = tl + i * 4;
            f4 kv = (f4){0.f, 0.f, 0.f, 0.f};
            if (t < T_CACHE) {
                kv = __builtin_nontemporal_load(kbase + i * 64);
                __builtin_nontemporal_store(kv, Kb + i * 64);
            }
            if (i < nat) {
                float ss = kv.x * q4.x + kv.y * q4.y + kv.z * q4.z + kv.w * q4.w;
                ss += __shfl_xor(ss, 1);
                ss += __shfl_xor(ss, 2);
                ss += __shfl_xor(ss, 4);
                ss += __shfl_xor(ss, 8);
                // token 2047 (the new token) is handled by combine_kernel
                s[i] = (t < slen && t < T_CACHE) ? ss * QK_SCALE : -1e30f;
            }
        }
    }

    // ---- softmax weights (exact chunk max, single exp per window) --------
    float m = -1e30f;
#pragma unroll
    for (int i = 0; i < 16; ++i)
        if (i < nat) m = fmaxf(m, s[i]);
    m = fmaxf(m, __shfl_xor(m, 16));
    m = fmaxf(m, __shfl_xor(m, 32));   // wave-uniform chunk max

    float l = 0.f;
#pragma unroll
    for (int i = 0; i < 16; ++i)
        if (i < nat) {
            const float p = __expf(s[i] - m);   // masked: exp(-huge) == 0
            s[i] = p;
            l += p;
        }

    // ---- Phase V: copy + weighted accumulate -----------------------------
    f4 o = {0.f, 0.f, 0.f, 0.f};
    if (!tail) {
#pragma unroll
        for (int i = 0; i < 16; ++i) {
            const f4 vv = __builtin_nontemporal_load(vbase + i * 64);
            __builtin_nontemporal_store(vv, Vb + i * 64);
            if (i < nat) {
                o.x = fmaf(s[i], vv.x, o.x);
                o.y = fmaf(s[i], vv.y, o.y);
                o.z = fmaf(s[i], vv.z, o.z);
                o.w = fmaf(s[i], vv.w, o.w);
            }
        }
    } else {
#pragma unroll
        for (int i = 0; i < 16; ++i) {
            const int t = tl + i * 4;
            f4 vv = (f4){0.f, 0.f, 0.f, 0.f};
            if (t < T_CACHE) {
                vv = __builtin_nontemporal_load(vbase + i * 64);
                __builtin_nontemporal_store(vv, Vb + i * 64);
            }
            if (i < nat) {
                o.x = fmaf(s[i], vv.x, o.x);
                o.y = fmaf(s[i], vv.y, o.y);
                o.z = fmaf(s[i], vv.z, o.z);
                o.w = fmaf(s[i], vv.w, o.w);
            }
        }
    }

    // merge l and o across the 4 token groups
    l += __shfl_xor(l, 16); l += __shfl_xor(l, 32);
    o.x += __shfl_xor(o.x, 16); o.x += __shfl_xor(o.x, 32);
    o.y += __shfl_xor(o.y, 16); o.y += __shfl_xor(o.y, 32);
    o.z += __shfl_xor(o.z, 16); o.z += __shfl_xor(o.z, 32);
    o.w += __shfl_xor(o.w, 16); o.w += __shfl_xor(o.w, 32);

    __shared__ float sm[4], sl[4];
    __shared__ f4 so4[4][16];
    if (lane == 0) { sm[wave] = m; sl[wave] = l; }
    if (lane < 16) so4[wave][dgrp] = o;
    __syncthreads();

    if (tid < HD) {
        const int d = tid;
        const float m0 = sm[0], m1 = sm[1], m2 = sm[2], m3 = sm[3];
        const float mc = fmaxf(fmaxf(m0, m1), fmaxf(m2, m3));
        const float e0 = __expf(m0 - mc), e1 = __expf(m1 - mc);
        const float e2 = __expf(m2 - mc), e3 = __expf(m3 - mc);
        const float lc = sl[0]*e0 + sl[1]*e1 + sl[2]*e2 + sl[3]*e3;
        const float* so = (const float*)so4;   // [4][64]
        const float oc = so[0*HD + d]*e0 + so[1*HD + d]*e1
                       + so[2*HD + d]*e2 + so[3*HD + d]*e3;
        const int pb = bh * NCHUNK + chunk;
        Po[(size_t)pb * HD + d] = oc;
        if (d == 0) { Pm[pb] = mc; Pl[pb] = lc; }
    }
}

// ---------------------------------------------------------------------------
// Combine chunk partials + the always-visible new token; also append the new
// k/v row to the output caches. grid = 512 (b*NH+h), block = 64 (one wave).
// ---------------------------------------------------------------------------
__global__ __launch_bounds__(64) void combine_kernel(
    const float* __restrict__ qkv,
    const float* __restrict__ Pm, const float* __restrict__ Pl,
    const float* __restrict__ Po,
    float* __restrict__ attn, float* __restrict__ Kout, float* __restrict__ Vout)
{
    const int bh = blockIdx.x;
    const int b = bh >> 4, h = bh & 15;
    const int d = threadIdx.x;     // 0..63

    const float* qb = qkv + (size_t)b * H3;
    const float qd = qb[h * HD + d];
    const float kn = qb[HID  + h * HD + d];
    const float vn = qb[2*HID + h * HD + d];

    // append new token row (position T_ALL-1)
    Kout[((size_t)bh * T_ALL + (T_ALL - 1)) * HD + d] = kn;
    Vout[((size_t)bh * T_ALL + (T_ALL - 1)) * HD + d] = vn;

    // new-token score (always valid)
    float s = qd * kn;
    s += __shfl_xor(s, 1);
    s += __shfl_xor(s, 2);
    s += __shfl_xor(s, 4);
    s += __shfl_xor(s, 8);
    s += __shfl_xor(s, 16);
    s += __shfl_xor(s, 32);
    s *= QK_SCALE;

    float mg = s;
#pragma unroll
    for (int c = 0; c < NCHUNK; ++c)
        mg = fmaxf(mg, Pm[bh * NCHUNK + c]);

    float L   = __expf(s - mg);   // p_new
    float acc = L * vn;
#pragma unroll
    for (int c = 0; c < NCHUNK; ++c) {
        const float e = __expf(Pm[bh * NCHUNK + c] - mg);
        acc += Po[(size_t)(bh * NCHUNK + c) * HD + d] * e;
        L   += Pl[bh * NCHUNK + c] * e;
    }
    attn[(size_t)b * HID + h * HD + d] = acc / L;
}

// ---------------------------------------------------------------------------
extern "C" void kernel_launch(void* const* d_in, const int* in_sizes, int n_in,
                              void* d_out, int out_size, void* d_ws, size_t ws_size,
                              hipStream_t stream)
{
    const float* hs       = (const float*)d_in[0];   // [32,1,1024]
    const float* kc       = (const float*)d_in[1];   // [32,16,2047,64]
    const float* vc       = (const float*)d_in[2];   // [32,16,2047,64]
    // d_in[3] block_tables: unused by the reference math
    const int*   seq_lens = (const int*)d_in[4];     // [32]
    // d_in[5] max_seq_len: == 2048, hardcoded
    const float* W_attn   = (const float*)d_in[6];   // [1024,3072]
    const float* b_attn   = (const float*)d_in[7];   // [3072]
    const float* W_proj   = (const float*)d_in[8];   // [1024,1024]
    const float* b_proj   = (const float*)d_in[9];   // [1024]

    float* out_attn = (float*)d_out;                           // 32*1024
    float* Kout = out_attn + (size_t)BATCH * HID;              // 32*16*2048*64
    float* Vout = Kout + (size_t)BATCH * NH * T_ALL * HD;

    // workspace layout (floats)
    float* w = (float*)d_ws;
    float* w_qkv_part  = w;                       // 8*32*3072  = 786432
    float* w_qkv       = w_qkv_part + (size_t)KSPLIT * BATCH * H3;   // 98304
    float* w_Pm        = w_qkv + (size_t)BATCH * H3;                 // 4096
    float* w_Pl        = w_Pm + BATCH * NH * NCHUNK;                 // 4096
    float* w_Po        = w_Pl + BATCH * NH * NCHUNK;                 // 262144
    float* w_attnvec   = w_Po + (size_t)BATCH * NH * NCHUNK * HD;    // 32768
    float* w_proj_part = w_attnvec + (size_t)BATCH * HID;            // 262144

    // 1) qkv = hs @ W_attn + b_attn   (192 blocks, 16 batches/thread)
    gemv_part_kernel<16><<<dim3(H3 / 256, KSPLIT, 2), 256, 0, stream>>>(
        hs, W_attn, w_qkv_part, H3, HID);
    gemv_reduce_kernel<<<dim3(H3 / 4 / 256, BATCH), 256, 0, stream>>>(
        w_qkv_part, b_attn, w_qkv, H3);

    // 2) fused cache copy + flash-decoding chunks
    fused_copy_attn_kernel<<<dim3(NCHUNK, NH, BATCH), 256, 0, stream>>>(
        kc, vc, w_qkv, seq_lens, Kout, Vout, w_Pm, w_Pl, w_Po);

    // 3) combine partials + new token, append new k/v rows
    combine_kernel<<<dim3(BATCH * NH), 64, 0, stream>>>(
        w_qkv, w_Pm, w_Pl, w_Po, w_attnvec, Kout, Vout);

    // 4) out = attn @ W_proj + b_proj  (128 blocks, 8 batches/thread)
    gemv_part_kernel<8><<<dim3(HID / 256, KSPLIT, 4), 256, 0, stream>>>(
        w_attnvec, W_proj, w_proj_part, HID, HID);
    gemv_reduce_kernel<<<dim3(HID / 4 / 256, BATCH), 256, 0, stream>>>(
        w_proj_part, b_proj, out_attn, HID);
}

// Round 3
// 251.332 us; speedup vs baseline: 1.9609x; 1.0812x over previous
//
#include <hip/hip_runtime.h>
#include <math.h>

// Problem constants (GPT2 decode attention, fp32)
#define BATCH   32
#define NH      16
#define HD      64      // head dim
#define T_ALL   2048    // cached 2047 + 1 new
#define T_CACHE 2047
#define HID     1024
#define H3      3072
#define QK_SCALE 0.125f // 64^-0.5
#define NCHUNK  16      // token chunks per (b,h) for flash-decoding split
#define CHTOK   128     // tokens per chunk
#define NWIN    8       // 4-token windows per wave (32 tokens/wave)
#define KSPLIT  8       // k-split for the GEMV kernels

// native 16B vector
typedef float f4 __attribute__((ext_vector_type(4)));

// ---------------------------------------------------------------------------
// GEMV part: out_part[ks][b][c] = sum_{k in split ks} X[b][k] * W[k][c]
// batch split across blockIdx.z; per-column k-order unchanged -> bit-exact.
// ---------------------------------------------------------------------------
template<int NB>
__global__ __launch_bounds__(256) void gemv_part_kernel(
    const float* __restrict__ X, const float* __restrict__ W,
    float* __restrict__ part, int N, int Kdim)
{
    const int c  = blockIdx.x * 256 + threadIdx.x;
    const int ks = blockIdx.y;
    const int b0 = blockIdx.z * NB;
    const int kchunk = Kdim / KSPLIT;
    float acc[NB];
#pragma unroll
    for (int j = 0; j < NB; ++j) acc[j] = 0.f;
    const int k0 = ks * kchunk;
#pragma unroll 16
    for (int k = k0; k < k0 + kchunk; ++k) {
        const float w = W[(size_t)k * N + c];
#pragma unroll
        for (int j = 0; j < NB; ++j)
            acc[j] = fmaf(X[(b0 + j) * Kdim + k], w, acc[j]);
    }
#pragma unroll
    for (int j = 0; j < NB; ++j)
        part[((size_t)ks * BATCH + b0 + j) * N + c] = acc[j];
}

// float4 reduce (bit-exact per element: bias first, then ks ascending)
__global__ __launch_bounds__(256) void gemv_reduce_kernel(
    const float* __restrict__ part, const float* __restrict__ bias,
    float* __restrict__ out, int N)
{
    const int c4 = blockIdx.x * 256 + threadIdx.x;
    const int b  = blockIdx.y;
    const int N4 = N >> 2;
    f4 acc = ((const f4*)bias)[c4];
#pragma unroll
    for (int ks = 0; ks < KSPLIT; ++ks) {
        const f4 p = ((const f4*)part)[((size_t)ks * BATCH + b) * N4 + c4];
        acc.x += p.x; acc.y += p.y; acc.z += p.z; acc.w += p.w;
    }
    ((f4*)out)[(size_t)b * N4 + c4] = acc;
}

// ---------------------------------------------------------------------------
// Fused cache-copy + flash-decoding attention chunk, v4.
// grid = (NCHUNK=16, NH, BATCH) = 8192 blocks, block = 256 (4 waves).
// Wave owns 32 tokens = 8 windows of (4 tokens x 16 f4-groups).
//
// v4: ALL 8 K-loads AND all 8 V-loads are issued upfront (16 loads = 4 KB
// in flight per wave). Scores consume only K, so the V-load stream covers
// the entire score/softmax compute burst -> no dead memory time per wave.
// NCHUNK doubled to 16 for 2x block-level parallelism.
// ---------------------------------------------------------------------------
__global__ __launch_bounds__(256, 4) void fused_copy_attn_kernel(
    const float* __restrict__ kc, const float* __restrict__ vc,
    const float* __restrict__ qkv, const int* __restrict__ seq_lens,
    float* __restrict__ Kout, float* __restrict__ Vout,
    float* __restrict__ Pm, float* __restrict__ Pl, float* __restrict__ Po)
{
    const int chunk = blockIdx.x;
    const int h     = blockIdx.y;
    const int b     = blockIdx.z;
    const int tid   = threadIdx.x;
    const int wave  = tid >> 6;
    const int lane  = tid & 63;
    const int dgrp  = lane & 15;   // which float4 of the 64-dim row
    const int tgrp  = lane >> 4;   // which of 4 tokens per window

    const int bh   = b * NH + h;
    const int slen = seq_lens[b];

    const f4 q4 = ((const f4*)(qkv + (size_t)b * H3 + h * HD))[dgrp];

    const int t0 = chunk * CHTOK + wave * (NWIN * 4);
    const int tl = t0 + tgrp;                       // this lane's first token
    const int nat  = min(NWIN, max(0, (slen - t0 + 3) >> 2));
    const bool tail = (t0 + NWIN * 4 - 1 >= T_CACHE);  // single tail wave

    const f4* kbase = (const f4*)(kc + (size_t)bh * T_CACHE * HD) + (size_t)tl * 16 + dgrp;
    const f4* vbase = (const f4*)(vc + (size_t)bh * T_CACHE * HD) + (size_t)tl * 16 + dgrp;
    f4* Kb = (f4*)(Kout + (size_t)bh * T_ALL * HD) + (size_t)tl * 16 + dgrp;
    f4* Vb = (f4*)(Vout + (size_t)bh * T_ALL * HD) + (size_t)tl * 16 + dgrp;

    f4 kreg[NWIN], vreg[NWIN];
    float s[NWIN];

    if (!tail) {
        // ---- issue ALL loads upfront: 16 in flight per wave --------------
#pragma unroll
        for (int i = 0; i < NWIN; ++i)
            kreg[i] = __builtin_nontemporal_load(kbase + i * 64);
#pragma unroll
        for (int i = 0; i < NWIN; ++i)
            vreg[i] = __builtin_nontemporal_load(vbase + i * 64);

        // ---- K: store + scores (V loads still in flight) -----------------
#pragma unroll
        for (int i = 0; i < NWIN; ++i) {
            __builtin_nontemporal_store(kreg[i], Kb + i * 64);
            if (i < nat) {
                const f4 kv = kreg[i];
                float ss = kv.x * q4.x + kv.y * q4.y + kv.z * q4.z + kv.w * q4.w;
                ss += __shfl_xor(ss, 1);
                ss += __shfl_xor(ss, 2);
                ss += __shfl_xor(ss, 4);
                ss += __shfl_xor(ss, 8);
                s[i] = (tl + i * 4 < slen) ? ss * QK_SCALE : -1e30f;
            }
        }
    } else {
#pragma unroll
        for (int i = 0; i < NWIN; ++i) {
            const int t = tl + i * 4;
            kreg[i] = (f4){0.f, 0.f, 0.f, 0.f};
            vreg[i] = (f4){0.f, 0.f, 0.f, 0.f};
            if (t < T_CACHE) {
                kreg[i] = __builtin_nontemporal_load(kbase + i * 64);
                vreg[i] = __builtin_nontemporal_load(vbase + i * 64);
            }
        }
#pragma unroll
        for (int i = 0; i < NWIN; ++i) {
            const int t = tl + i * 4;
            if (t < T_CACHE)
                __builtin_nontemporal_store(kreg[i], Kb + i * 64);
            if (i < nat) {
                const f4 kv = kreg[i];
                float ss = kv.x * q4.x + kv.y * q4.y + kv.z * q4.z + kv.w * q4.w;
                ss += __shfl_xor(ss, 1);
                ss += __shfl_xor(ss, 2);
                ss += __shfl_xor(ss, 4);
                ss += __shfl_xor(ss, 8);
                // token 2047 (the new token) is handled by combine_kernel
                s[i] = (t < slen && t < T_CACHE) ? ss * QK_SCALE : -1e30f;
            }
        }
    }

    // ---- softmax weights (exact chunk max, single exp per window) --------
    float m = -1e30f;
#pragma unroll
    for (int i = 0; i < NWIN; ++i)
        if (i < nat) m = fmaxf(m, s[i]);
    m = fmaxf(m, __shfl_xor(m, 16));
    m = fmaxf(m, __shfl_xor(m, 32));   // wave-uniform chunk max

    float l = 0.f;
#pragma unroll
    for (int i = 0; i < NWIN; ++i)
        if (i < nat) {
            const float p = __expf(s[i] - m);   // masked: exp(-huge) == 0
            s[i] = p;
            l += p;
        }

    // ---- V: store + weighted accumulate ----------------------------------
    f4 o = {0.f, 0.f, 0.f, 0.f};
    if (!tail) {
#pragma unroll
        for (int i = 0; i < NWIN; ++i) {
            __builtin_nontemporal_store(vreg[i], Vb + i * 64);
            if (i < nat) {
                o.x = fmaf(s[i], vreg[i].x, o.x);
                o.y = fmaf(s[i], vreg[i].y, o.y);
                o.z = fmaf(s[i], vreg[i].z, o.z);
                o.w = fmaf(s[i], vreg[i].w, o.w);
            }
        }
    } else {
#pragma unroll
        for (int i = 0; i < NWIN; ++i) {
            const int t = tl + i * 4;
            if (t < T_CACHE)
                __builtin_nontemporal_store(vreg[i], Vb + i * 64);
            if (i < nat) {
                o.x = fmaf(s[i], vreg[i].x, o.x);
                o.y = fmaf(s[i], vreg[i].y, o.y);
                o.z = fmaf(s[i], vreg[i].z, o.z);
                o.w = fmaf(s[i], vreg[i].w, o.w);
            }
        }
    }

    // merge l and o across the 4 token groups
    l += __shfl_xor(l, 16); l += __shfl_xor(l, 32);
    o.x += __shfl_xor(o.x, 16); o.x += __shfl_xor(o.x, 32);
    o.y += __shfl_xor(o.y, 16); o.y += __shfl_xor(o.y, 32);
    o.z += __shfl_xor(o.z, 16); o.z += __shfl_xor(o.z, 32);
    o.w += __shfl_xor(o.w, 16); o.w += __shfl_xor(o.w, 32);

    __shared__ float sm[4], sl[4];
    __shared__ f4 so4[4][16];
    if (lane == 0) { sm[wave] = m; sl[wave] = l; }
    if (lane < 16) so4[wave][dgrp] = o;
    __syncthreads();

    if (tid < HD) {
        const int d = tid;
        const float m0 = sm[0], m1 = sm[1], m2 = sm[2], m3 = sm[3];
        const float mc = fmaxf(fmaxf(m0, m1), fmaxf(m2, m3));
        const float e0 = __expf(m0 - mc), e1 = __expf(m1 - mc);
        const float e2 = __expf(m2 - mc), e3 = __expf(m3 - mc);
        const float lc = sl[0]*e0 + sl[1]*e1 + sl[2]*e2 + sl[3]*e3;
        const float* so = (const float*)so4;   // [4][64]
        const float oc = so[0*HD + d]*e0 + so[1*HD + d]*e1
                       + so[2*HD + d]*e2 + so[3*HD + d]*e3;
        const int pb = bh * NCHUNK + chunk;
        Po[(size_t)pb * HD + d] = oc;
        if (d == 0) { Pm[pb] = mc; Pl[pb] = lc; }
    }
}

// ---------------------------------------------------------------------------
// Combine chunk partials + the always-visible new token; also append the new
// k/v row to the output caches. grid = 512 (b*NH+h), block = 64 (one wave).
// ---------------------------------------------------------------------------
__global__ __launch_bounds__(64) void combine_kernel(
    const float* __restrict__ qkv,
    const float* __restrict__ Pm, const float* __restrict__ Pl,
    const float* __restrict__ Po,
    float* __restrict__ attn, float* __restrict__ Kout, float* __restrict__ Vout)
{
    const int bh = blockIdx.x;
    const int b = bh >> 4, h = bh & 15;
    const int d = threadIdx.x;     // 0..63

    const float* qb = qkv + (size_t)b * H3;
    const float qd = qb[h * HD + d];
    const float kn = qb[HID  + h * HD + d];
    const float vn = qb[2*HID + h * HD + d];

    // append new token row (position T_ALL-1)
    Kout[((size_t)bh * T_ALL + (T_ALL - 1)) * HD + d] = kn;
    Vout[((size_t)bh * T_ALL + (T_ALL - 1)) * HD + d] = vn;

    // new-token score (always valid)
    float s = qd * kn;
    s += __shfl_xor(s, 1);
    s += __shfl_xor(s, 2);
    s += __shfl_xor(s, 4);
    s += __shfl_xor(s, 8);
    s += __shfl_xor(s, 16);
    s += __shfl_xor(s, 32);
    s *= QK_SCALE;

    float mg = s;
#pragma unroll
    for (int c = 0; c < NCHUNK; ++c)
        mg = fmaxf(mg, Pm[bh * NCHUNK + c]);

    float L   = __expf(s - mg);   // p_new
    float acc = L * vn;
#pragma unroll
    for (int c = 0; c < NCHUNK; ++c) {
        const float e = __expf(Pm[bh * NCHUNK + c] - mg);
        acc += Po[(size_t)(bh * NCHUNK + c) * HD + d] * e;
        L   += Pl[bh * NCHUNK + c] * e;
    }
    attn[(size_t)b * HID + h * HD + d] = acc / L;
}

// ---------------------------------------------------------------------------
extern "C" void kernel_launch(void* const* d_in, const int* in_sizes, int n_in,
                              void* d_out, int out_size, void* d_ws, size_t ws_size,
                              hipStream_t stream)
{
    const float* hs       = (const float*)d_in[0];   // [32,1,1024]
    const float* kc       = (const float*)d_in[1];   // [32,16,2047,64]
    const float* vc       = (const float*)d_in[2];   // [32,16,2047,64]
    // d_in[3] block_tables: unused by the reference math
    const int*   seq_lens = (const int*)d_in[4];     // [32]
    // d_in[5] max_seq_len: == 2048, hardcoded
    const float* W_attn   = (const float*)d_in[6];   // [1024,3072]
    const float* b_attn   = (const float*)d_in[7];   // [3072]
    const float* W_proj   = (const float*)d_in[8];   // [1024,1024]
    const float* b_proj   = (const float*)d_in[9];   // [1024]

    float* out_attn = (float*)d_out;                           // 32*1024
    float* Kout = out_attn + (size_t)BATCH * HID;              // 32*16*2048*64
    float* Vout = Kout + (size_t)BATCH * NH * T_ALL * HD;

    // workspace layout (floats)
    float* w = (float*)d_ws;
    float* w_qkv_part  = w;                       // 8*32*3072  = 786432
    float* w_qkv       = w_qkv_part + (size_t)KSPLIT * BATCH * H3;   // 98304
    float* w_Pm        = w_qkv + (size_t)BATCH * H3;                 // 8192
    float* w_Pl        = w_Pm + BATCH * NH * NCHUNK;                 // 8192
    float* w_Po        = w_Pl + BATCH * NH * NCHUNK;                 // 524288
    float* w_attnvec   = w_Po + (size_t)BATCH * NH * NCHUNK * HD;    // 32768
    float* w_proj_part = w_attnvec + (size_t)BATCH * HID;            // 262144

    // 1) qkv = hs @ W_attn + b_attn   (192 blocks, 16 batches/thread)
    gemv_part_kernel<16><<<dim3(H3 / 256, KSPLIT, 2), 256, 0, stream>>>(
        hs, W_attn, w_qkv_part, H3, HID);
    gemv_reduce_kernel<<<dim3(H3 / 4 / 256, BATCH), 256, 0, stream>>>(
        w_qkv_part, b_attn, w_qkv, H3);

    // 2) fused cache copy + flash-decoding chunks
    fused_copy_attn_kernel<<<dim3(NCHUNK, NH, BATCH), 256, 0, stream>>>(
        kc, vc, w_qkv, seq_lens, Kout, Vout, w_Pm, w_Pl, w_Po);

    // 3) combine partials + new token, append new k/v rows
    combine_kernel<<<dim3(BATCH * NH), 64, 0, stream>>>(
        w_qkv, w_Pm, w_Pl, w_Po, w_attnvec, Kout, Vout);

    // 4) out = attn @ W_proj + b_proj  (128 blocks, 8 batches/thread)
    gemv_part_kernel<8><<<dim3(HID / 256, KSPLIT, 4), 256, 0, stream>>>(
        w_attnvec, W_proj, w_proj_part, HID, HID);
    gemv_reduce_kernel<<<dim3(HID / 4 / 256, BATCH), 256, 0, stream>>>(
        w_proj_part, b_proj, out_attn, HID);
}